// Round 19
// baseline (714.467 us; speedup 1.0000x reference)
//
#include <hip/hip_runtime.h>
#include <utility>

// reference == inverse(M M^T + EPS*I) per pixel, M = x[b,:,:,h,w]^T (16x64)
// x: [B=4, C=64, K=16, H=128, W=128] f32 ; out: [B,H,W,16,16] f32
// Round 19: 1-WAY SPLIT — thread = pixel, full acc[136] in registers.
//   kills: 2x LDS-read redundancy, tri[] LDS round-trip, phase-2, separate s[136]
//   512 blocks x 128 threads (2 waves); px = blockIdx*128 + tid (512 B bursts kept)
//   phase 1: gram via global_load_lds dbuf, chunk = 2c x 16k x 128px = 16 KB
//            each (px,c) m[16] read by exactly ONE thread (no redundancy)
//   phase 2: regularize + REGISTER Cholesky -> L^-1 -> M^T M directly on acc
//   phase 3: direct per-thread float4 stores (r1-verified epilogue; each thread
//            writes its own contiguous 1 KB row of out)
// LDS: stage 2x16KB = 32 KB only. __launch_bounds__(128,2) -> 256-VGPR cap;
// est. live = 136 acc + 16 m + ~20 addr ~= 175. ABORT if VGPR<150 (spill).

#define EPSR 1e-6f

__device__ __host__ constexpr int rowof(int t) {
    int i = 0;
    while ((i + 1) * (i + 2) / 2 <= t) ++i;
    return i;
}
__device__ __host__ constexpr int colof(int t) { return t - rowof(t) * (rowof(t) + 1) / 2; }

__device__ __forceinline__ constexpr int tidx(int i, int j) {  // i >= j
    return i * (i + 1) / 2 + j;
}

#define GLOAD_LDS16(gp, lp)                                                       \
    __builtin_amdgcn_global_load_lds(                                             \
        (const __attribute__((address_space(1))) void*)(gp),                      \
        (__attribute__((address_space(3))) void*)(lp), 16, 0, 0)

// ---------------- flat 136-pair FMA chain ----------------

template<int P>
__device__ __forceinline__ void fma_pair(const float (&m)[16], float& a) {
    a = fmaf(m[rowof(P)], m[colof(P)], a);
}

template<int... TT>
__device__ __forceinline__ void fma_all(const float (&m)[16], float (&acc)[136],
                                        std::integer_sequence<int, TT...>) {
    (fma_pair<TT>(m, acc[TT]), ...);
}

// ---------------- fused kernel ----------------

__global__ __launch_bounds__(128, 2)
void fused_gram_inv(const float* __restrict__ x, float* __restrict__ out) {
    __shared__ __align__(16) float stage[2][4096];   // 2 x 16 KB: [c'*2048 + k*128 + px]

    const int tid = threadIdx.x;                     // = px within block, 0..127
    const int lane = tid & 63;
    const int wv = tid >> 6;                         // 0 or 1
    const int p0 = blockIdx.x * 128;
    const int b = blockIdx.x >> 7;                   // 128 blocks per batch
    const int hw0 = p0 & 16383;

    // staging src: lane l covers k-row (l>>5), px (l&31)*4..+3  (16 B/lane ->
    // one instr = 2 k-rows x 128 px = 1 KB lane-linear, 512 B contiguous/row)
    const float* gbase = x + (size_t)b * 16777216 + hw0
                           + (size_t)(lane >> 5) * 16384 + (size_t)(lane & 31) * 4;

    float acc[136];
    #pragma unroll
    for (int t = 0; t < 136; ++t) acc[t] = 0.0f;

    // chunk t = channels {2t, 2t+1}; wave wv stages c' = wv: 8 instrs x 1 KB
    auto STAGE = [&](int bufi, int t) {
        const float* gp = gbase + (size_t)(2 * t + wv) * 262144;
        #pragma unroll
        for (int q = 0; q < 8; ++q) {
            GLOAD_LDS16(gp + (size_t)(q * 2) * 16384,
                        &stage[bufi][wv * 2048 + (q * 2) * 128]);
        }
    };

    // ---- phase 1: gram, dbuf pipeline (32 chunks of 2 c) ----
    STAGE(0, 0);
    for (int t = 0; t < 32; ++t) {
        __syncthreads();                             // vmcnt(0) drain + barrier
        if (t < 31) STAGE((t + 1) & 1, t + 1);       // prefetch next chunk
        const float* buf = stage[t & 1];
        #pragma unroll
        for (int cs = 0; cs < 2; ++cs) {
            float m[16];
            #pragma unroll
            for (int k = 0; k < 16; ++k) m[k] = buf[cs * 2048 + k * 128 + tid];
            fma_all(m, acc, std::make_integer_sequence<int, 136>{});
        }
    }

    // ---- phase 2: regularize + in-register inversion (acc IS the workspace) ----
    #pragma unroll
    for (int i = 0; i < 16; ++i) acc[tidx(i, i)] += EPSR;

    // Cholesky in place: off-diag = L[i][j], diag = 1/L[j][j]
    #pragma unroll
    for (int j = 0; j < 16; ++j) {
        float d = acc[tidx(j, j)];
        #pragma unroll
        for (int q = 0; q < j; ++q) d = fmaf(-acc[tidx(j, q)], acc[tidx(j, q)], d);
        const float invd = 1.0f / sqrtf(d);
        acc[tidx(j, j)] = invd;
        #pragma unroll
        for (int i = j + 1; i < 16; ++i) {
            float v = acc[tidx(i, j)];
            #pragma unroll
            for (int q = 0; q < j; ++q) v = fmaf(-acc[tidx(i, q)], acc[tidx(j, q)], v);
            acc[tidx(i, j)] = v * invd;
        }
    }

    // M = L^{-1} in place (diag already inverted)
    #pragma unroll
    for (int j = 0; j < 16; ++j) {
        #pragma unroll
        for (int i = j + 1; i < 16; ++i) {
            float sum = acc[tidx(i, j)] * acc[tidx(j, j)];
            #pragma unroll
            for (int q = j + 1; q < i; ++q)
                sum = fmaf(acc[tidx(i, q)], acc[tidx(q, j)], sum);
            acc[tidx(i, j)] = -acc[tidx(i, i)] * sum;
        }
    }

    // A^{-1} = M^T M in place
    #pragma unroll
    for (int j = 0; j < 16; ++j) {
        #pragma unroll
        for (int i = j; i < 16; ++i) {
            float sum = 0.0f;
            #pragma unroll
            for (int q = i; q < 16; ++q)
                sum = fmaf(acc[tidx(q, i)], acc[tidx(q, j)], sum);
            acc[tidx(i, j)] = sum;
        }
    }

    // ---- phase 3: direct float4 stores, thread owns its 1 KB output row ----
    float* op = out + (size_t)(p0 + tid) * 256;
    #pragma unroll
    for (int i = 0; i < 16; ++i) {
        #pragma unroll
        for (int jq = 0; jq < 4; ++jq) {
            const int j0 = jq * 4;
            float4 v;
            v.x = (i >= j0 + 0) ? acc[tidx(i, j0 + 0)] : acc[tidx(j0 + 0, i)];
            v.y = (i >= j0 + 1) ? acc[tidx(i > j0 + 1 ? i : j0 + 1, i > j0 + 1 ? j0 + 1 : i)] : acc[tidx(j0 + 1, i)];
            v.z = (i >= j0 + 2) ? acc[tidx(i > j0 + 2 ? i : j0 + 2, i > j0 + 2 ? j0 + 2 : i)] : acc[tidx(j0 + 2, i)];
            v.w = (i >= j0 + 3) ? acc[tidx(i > j0 + 3 ? i : j0 + 3, i > j0 + 3 ? j0 + 3 : i)] : acc[tidx(j0 + 3, i)];
            *reinterpret_cast<float4*>(op + i * 16 + j0) = v;
        }
    }
}

extern "C" void kernel_launch(void* const* d_in, const int* in_sizes, int n_in,
                              void* d_out, int out_size, void* d_ws, size_t ws_size,
                              hipStream_t stream) {
    const float* x = (const float*)d_in[0];
    float* out = (float*)d_out;
    hipLaunchKernelGGL(fused_gram_inv, dim3(512), dim3(128), 0, stream, x, out);
}

// Round 20
// 71.507 us; speedup vs baseline: 9.9916x; 9.9916x over previous
//
#include <hip/hip_runtime.h>
#include <utility>

// reference == inverse(M M^T + EPS*I) per pixel, M = x[b,:,:,h,w]^T (16x64)
// x: [B=4, C=64, K=16, H=128, W=128] f32 ; out: [B,H,W,16,16] f32
// FINAL (= round-17 best, 70.6 us): fused, 128 px/block, 512 blocks, 256 threads.
//   wave wv -> (G = wv&1: pair group, ph = wv>>1: pixel half), px = ph*64+lane
//   phase 1: gram via global_load_lds dbuf; chunk = 4c x 16k x 128px = 32 KB
//            (512 B contiguous burst per staged row -- measured optimum)
//   phase 2: acc[68] -> tri[136][131] (+EPS diag)
//   phase 3: G==0 waves: tri -> REGISTER Cholesky -> L^-1 -> M^T M -> tri
//   phase 4: gather-store (thread = element, loop 128 px, coalesced)
// LDS: union{stage 2x32KB, tri 71.3KB} = 71.3KB -> 2 blocks/CU, 2 waves/SIMD.
// Search-space summary (19 rounds): pipeline depth x3, chunk/MLP, burst x2,
// split arity x3, direct-global, gen-overlap x2 all tested single-variable;
// this structure is the measured optimum. acc[136]-in-registers spills (x3).

#define EPSR 1e-6f
#define TS2 131                    // tri row stride; 131 mod 32 = 3 (bank spread)

__device__ __host__ constexpr int rowof(int t) {
    int i = 0;
    while ((i + 1) * (i + 2) / 2 <= t) ++i;
    return i;
}
__device__ __host__ constexpr int colof(int t) { return t - rowof(t) * (rowof(t) + 1) / 2; }

__device__ __forceinline__ constexpr int tidx(int i, int j) {  // i >= j
    return i * (i + 1) / 2 + j;
}

#define GLOAD_LDS16(gp, lp)                                                       \
    __builtin_amdgcn_global_load_lds(                                             \
        (const __attribute__((address_space(1))) void*)(gp),                      \
        (__attribute__((address_space(3))) void*)(lp), 16, 0, 0)

// ---------------- pair-split template machinery (68/group) ----------------

template<int P>
__device__ __forceinline__ void fma_pair(const float (&m)[16], float& a) {
    a = fmaf(m[rowof(P)], m[colof(P)], a);
}

template<int G, int... TT>
__device__ __forceinline__ void fma_group(const float (&m)[16], float (&acc)[68],
                                          std::integer_sequence<int, TT...>) {
    (fma_pair<G * 68 + TT>(m, acc[TT]), ...);
}

template<int G>
__device__ __forceinline__ void chunk_fma4(const float* __restrict__ buf, int px,
                                           float (&acc)[68]) {
    #pragma unroll
    for (int crel = 0; crel < 4; ++crel) {
        float m[16];
        #pragma unroll
        for (int k = 0; k < 16; ++k) m[k] = buf[crel * 2048 + k * 128 + px];
        fma_group<G>(m, acc, std::make_integer_sequence<int, 68>{});
    }
}

template<int P>
__device__ __forceinline__ void store_tri_pair(float* __restrict__ tri, int px, float v) {
    constexpr bool diag = (rowof(P) == colof(P));
    tri[P * TS2 + px] = diag ? (v + EPSR) : v;
}

template<int G, int... TT>
__device__ __forceinline__ void store_tri_group(float* __restrict__ tri, int px,
                                                const float (&acc)[68],
                                                std::integer_sequence<int, TT...>) {
    (store_tri_pair<G * 68 + TT>(tri, px, acc[TT]), ...);
}

// ---------------- fused kernel ----------------

union SMem {
    float stage[2][8192];      // 2 x 32 KB: [crel(0..3)*2048 + k*128 + px]
    float tri[136 * TS2];      // 71.3 KB; row = pair index, col = pixel
};

__global__ __launch_bounds__(256, 2)
void fused_gram_inv(const float* __restrict__ x, float* __restrict__ out) {
    __shared__ __align__(16) SMem sm;

    const int tid = threadIdx.x;
    const int lane = tid & 63;
    const int wv = tid >> 6;                  // 0..3
    const int G = wv & 1;                     // pair group (0: pairs 0-67, 1: 68-135)
    const int ph = wv >> 1;                   // pixel half (0: px 0-63, 1: px 64-127)
    const int px = ph * 64 + lane;            // this thread's pixel
    const int p0 = blockIdx.x * 128;
    const int b = blockIdx.x >> 7;            // 128 blocks per batch
    const int hw0 = p0 & 16383;

    // staging src: lane l covers k-row (l>>5), px (l&31)*4..+3  (16 B/lane ->
    // one instr = 2 k-rows x 128 px = 1 KB lane-linear, 512 B contiguous/row)
    const float* gbase = x + (size_t)b * 16777216 + hw0
                           + (size_t)(lane >> 5) * 16384 + (size_t)(lane & 31) * 4;

    float acc[68];
    #pragma unroll
    for (int t = 0; t < 68; ++t) acc[t] = 0.0f;

    // chunk t = channels [4t, 4t+4); wave wv stages crel = wv (16k x 128px = 8 KB,
    // 8 instrs, instr q covers k-rows {2q, 2q+1})
    auto STAGE = [&](int bufi, int c0) {
        const float* gp = gbase + (size_t)(c0 + wv) * 262144;
        #pragma unroll
        for (int q = 0; q < 8; ++q) {
            GLOAD_LDS16(gp + (size_t)(q * 2) * 16384,
                        &sm.stage[bufi][wv * 2048 + (q * 2) * 128]);
        }
    };

    // ---- phase 1: gram, dbuf pipeline (16 chunks of 4 c) ----
    STAGE(0, 0);
    for (int t = 0; t < 16; ++t) {
        __syncthreads();                              // vmcnt(0) drain + barrier
        if (t < 15) STAGE((t + 1) & 1, 4 * (t + 1));  // prefetch next chunk
        const float* buf = sm.stage[t & 1];
        if (G == 0) chunk_fma4<0>(buf, px, acc);
        else        chunk_fma4<1>(buf, px, acc);
    }
    __syncthreads();   // all stage reads done before aliasing stage as tri

    // ---- phase 2: acc -> tri (+EPS on diag); disjoint (rows G, cols ph) ----
    if (G == 0) store_tri_group<0>(sm.tri, px, acc, std::make_integer_sequence<int, 68>{});
    else        store_tri_group<1>(sm.tri, px, acc, std::make_integer_sequence<int, 68>{});
    __syncthreads();

    // ---- phase 3: G==0 waves, lane = own px, REGISTER inversion ----
    if (G == 0) {
        float s[136];
        #pragma unroll
        for (int t = 0; t < 136; ++t) s[t] = sm.tri[t * TS2 + px];

        // Cholesky in place: off-diag = L[i][j], diag = 1/L[j][j]
        #pragma unroll
        for (int j = 0; j < 16; ++j) {
            float d = s[tidx(j, j)];
            #pragma unroll
            for (int q = 0; q < j; ++q) d = fmaf(-s[tidx(j, q)], s[tidx(j, q)], d);
            const float invd = 1.0f / sqrtf(d);
            s[tidx(j, j)] = invd;
            #pragma unroll
            for (int i = j + 1; i < 16; ++i) {
                float v = s[tidx(i, j)];
                #pragma unroll
                for (int q = 0; q < j; ++q) v = fmaf(-s[tidx(i, q)], s[tidx(j, q)], v);
                s[tidx(i, j)] = v * invd;
            }
        }

        // M = L^{-1} in place (diag already inverted)
        #pragma unroll
        for (int j = 0; j < 16; ++j) {
            #pragma unroll
            for (int i = j + 1; i < 16; ++i) {
                float sum = s[tidx(i, j)] * s[tidx(j, j)];
                #pragma unroll
                for (int q = j + 1; q < i; ++q)
                    sum = fmaf(s[tidx(i, q)], s[tidx(q, j)], sum);
                s[tidx(i, j)] = -s[tidx(i, i)] * sum;
            }
        }

        // A^{-1} = M^T M in place
        #pragma unroll
        for (int j = 0; j < 16; ++j) {
            #pragma unroll
            for (int i = j; i < 16; ++i) {
                float sum = 0.0f;
                #pragma unroll
                for (int q = i; q < 16; ++q)
                    sum = fmaf(s[tidx(q, i)], s[tidx(q, j)], sum);
                s[tidx(i, j)] = sum;
            }
        }

        // writeback
        #pragma unroll
        for (int t = 0; t < 136; ++t) sm.tri[t * TS2 + px] = s[t];
    }
    __syncthreads();

    // ---- phase 4: gather-store, thread = output element e, loop 128 px ----
    const int e = tid;                  // 0..255 -> (i,j)
    const int i = e >> 4, j = e & 15;
    const int hi = i > j ? i : j;
    const int lo = i + j - hi;
    const int trow = hi * (hi + 1) / 2 + lo;
    float* gout = out + (size_t)p0 * 256;
    #pragma unroll 8
    for (int a = 0; a < 128; ++a) {
        gout[(size_t)a * 256 + e] = sm.tri[trow * TS2 + a];
    }
}

extern "C" void kernel_launch(void* const* d_in, const int* in_sizes, int n_in,
                              void* d_out, int out_size, void* d_ws, size_t ws_size,
                              hipStream_t stream) {
    const float* x = (const float*)d_in[0];
    float* out = (float*)d_out;
    hipLaunchKernelGGL(fused_gram_inv, dim3(512), dim3(256), 0, stream, x, out);
}